// Round 4
// baseline (213.249 us; speedup 1.0000x reference)
//
#include <hip/hip_runtime.h>
#include <hip/hip_bf16.h>
#include <stdint.h>

// Problem constants (fixed by setup_inputs)
#define PRIME 2147483647u
#define GAMMA 0.3f
#define K_HASH 128
#define S_SET 8
#define NB 4
#define LQ 1024
#define LK 1024
#define EDIM 512
#define FIX_CAP (NB * LQ * LK)   // exact worst case: every pair touched once

typedef unsigned short ushort_t;
typedef __attribute__((ext_vector_type(8))) short short8;
typedef __attribute__((ext_vector_type(4))) float f32x4;

static __device__ __forceinline__ unsigned short f2bf(float f) {
    unsigned u = __builtin_bit_cast(unsigned, f);
    u += 0x7FFFu + ((u >> 16) & 1u);   // RNE (no NaN in this problem)
    return (unsigned short)(u >> 16);
}

// async global->LDS, 16B per lane; LDS dst must be lane-contiguous.
static __device__ __forceinline__ void glds16(const void* g, void* l) {
    __builtin_amdgcn_global_load_lds(
        (const __attribute__((address_space(1))) unsigned int*)g,
        (__attribute__((address_space(3))) unsigned int*)l, 16, 0, 0);
}

#define SWZ(r) ((((r) >> 2) & 3) ^ ((r) & 3))

// score(m) = exp(exp(-GAMMA * 2S * (K-m)/(K+m))), m = matched hash slots
static __device__ __forceinline__ float score_of(int m) {
    float r = (float)(K_HASH - m) / (float)(K_HASH + m);
    return expf(expf(-GAMMA * (2.0f * S_SET) * r));
}

// ---------------------------------------------------------------------------
// 64x64-tile bf16 BT-GEMM device fn: C=A@B^T (+epilogue), f32 accum,
// 4 waves x 32x32, glds width-16, XOR-swizzled LDS, double-buffered.
// ---------------------------------------------------------------------------
#define EPI_ROWBIAS  0   // v += bias[gm]
#define EPI_COLBIAS  2   // v += bias[gn]
#define EPI_NONE     3   // v unchanged
#define EPI_DIVBIAS  4   // v = v/scale[gm] + bias[gn]

template<int OUTF32, int MODE>
static __device__ void gemm64_dev(
        const ushort_t* __restrict__ A, const ushort_t* __restrict__ B,
        void* __restrict__ C,
        const float* __restrict__ bias, const float* __restrict__ scale,
        int lda, int ldb, int ldc, int Kd, int m0, int n0,
        ushort_t* AsBase, ushort_t* BsBase, int tid) {
    ushort_t (*As)[64 * 32] = (ushort_t (*)[64 * 32])AsBase;
    ushort_t (*Bs)[64 * 32] = (ushort_t (*)[64 * 32])BsBase;
    int w = tid >> 6, lane = tid & 63;
    int wm = (w & 1) * 32, wn = (w >> 1) * 32;
    int mrow = lane & 15, kg = lane >> 4;

    int r = tid >> 2, c = (tid & 3) ^ SWZ(r);
    const ushort_t* pa = A + (size_t)(m0 + r) * lda + c * 8;
    const ushort_t* pb = B + (size_t)(n0 + r) * ldb + c * 8;

    int aoff[2], boff[2];
    #pragma unroll
    for (int s = 0; s < 2; s++) {
        int Ra = wm + s * 16 + mrow;
        aoff[s] = Ra * 32 + (kg ^ SWZ(Ra)) * 8;
        int Rb = wn + s * 16 + mrow;
        boff[s] = Rb * 32 + (kg ^ SWZ(Rb)) * 8;
    }

    f32x4 acc[2][2] = {};
    int nK = Kd >> 5;
    glds16(pa, &As[0][tid * 8]);
    glds16(pb, &Bs[0][tid * 8]);
    for (int i = 0; i < nK; i++) {
        __syncthreads();
        int cur = i & 1, nxt = cur ^ 1;
        if (i + 1 < nK) {
            int k0 = (i + 1) << 5;
            glds16(pa + k0, &As[nxt][tid * 8]);
            glds16(pb + k0, &Bs[nxt][tid * 8]);
        }
        short8 af[2], bh[2];
        #pragma unroll
        for (int s = 0; s < 2; s++) {
            af[s] = *(const short8*)&As[cur][aoff[s]];
            bh[s] = *(const short8*)&Bs[cur][boff[s]];
        }
        #pragma unroll
        for (int ii = 0; ii < 2; ii++)
            #pragma unroll
            for (int jj = 0; jj < 2; jj++)
                acc[ii][jj] = __builtin_amdgcn_mfma_f32_16x16x32_bf16(
                                  af[ii], bh[jj], acc[ii][jj], 0, 0, 0);
    }

    int col = lane & 15, rbase = (lane >> 4) * 4;
    #pragma unroll
    for (int ii = 0; ii < 2; ii++) {
        #pragma unroll
        for (int jj = 0; jj < 2; jj++) {
            #pragma unroll
            for (int rr = 0; rr < 4; rr++) {
                int gm = m0 + wm + ii * 16 + rbase + rr;
                int gn = n0 + wn + jj * 16 + col;
                float v = acc[ii][jj][rr];
                if (MODE == EPI_ROWBIAS)      v += bias[gm];
                else if (MODE == EPI_COLBIAS) v += bias[gn];
                else if (MODE == EPI_DIVBIAS) v = v / scale[gm] + bias[gn];
                size_t cix = (size_t)gm * ldc + gn;
                if (OUTF32) ((float*)C)[cix] = v;
                else        ((ushort_t*)C)[cix] = f2bf(v);
            }
        }
    }
}

// ---------------------------------------------------------------------------
// 1) prep: f32->bf16 converts (value/Wv/Wo) + MinHash signatures (u32, exact)
//    + P prefill with bf16(score(0)) + M zero + rs fill + nfix zero.
// ---------------------------------------------------------------------------
#define CVT_N0 (NB * LK * EDIM)
#define CVT_N1 (EDIM * EDIM)
#define CVT_N2 (EDIM * EDIM)
#define CVT_BLOCKS ((CVT_N0 + CVT_N1 + CVT_N2) / (256 * 8))   // 1280
#define PF_BLOCKS 2048     // 8 MB P / 4 KB
#define MZ_BLOCKS 1024     // 4 MB M / 4 KB
#define RS_BLOCKS 16       // 4096 f32
#define SIG_BLOCKS (NB * (LQ + LK) / 2)                        // 4096
#define PREP_GRID (CVT_BLOCKS + PF_BLOCKS + MZ_BLOCKS + RS_BLOCKS + SIG_BLOCKS)

__global__ __launch_bounds__(256) void prep_kernel(
        const float* __restrict__ v, const float* __restrict__ wv,
        const float* __restrict__ wo,
        ushort_t* __restrict__ vb, ushort_t* __restrict__ wvb,
        ushort_t* __restrict__ wob,
        const int* __restrict__ ts_q, const int* __restrict__ ts_k,
        const int* __restrict__ ha, const int* __restrict__ hb,
        unsigned* __restrict__ sig_q, unsigned* __restrict__ sig_k,
        uint8_t* __restrict__ M, ushort_t* __restrict__ P,
        float* __restrict__ rs, unsigned* __restrict__ nfix) {
    int blk = blockIdx.x;
    if (blk < CVT_BLOCKS) {               // ---- convert branch ----
        size_t i = ((size_t)blk * 256 + threadIdx.x) * 8;
        const float* src; ushort_t* dst; size_t off;
        if (i < CVT_N0)                { src = v;  dst = vb;  off = i; }
        else if (i < CVT_N0 + CVT_N1)  { src = wv; dst = wvb; off = i - CVT_N0; }
        else                           { src = wo; dst = wob; off = i - CVT_N0 - CVT_N1; }
        float4 a = *(const float4*)(src + off);
        float4 b = *(const float4*)(src + off + 4);
        ushort4 o0, o1;
        o0.x = f2bf(a.x); o0.y = f2bf(a.y); o0.z = f2bf(a.z); o0.w = f2bf(a.w);
        o1.x = f2bf(b.x); o1.y = f2bf(b.y); o1.z = f2bf(b.z); o1.w = f2bf(b.w);
        *(ushort4*)(dst + off)     = o0;
        *(ushort4*)(dst + off + 4) = o1;
        return;
    }
    if (blk < CVT_BLOCKS + PF_BLOCKS) {   // ---- P prefill: bf16(score(0)) ----
        unsigned short pb = f2bf(score_of(0));
        unsigned wpat = (unsigned)pb | ((unsigned)pb << 16);
        size_t off = ((size_t)(blk - CVT_BLOCKS) * 256 + threadIdx.x) * 16;
        *(int4*)((char*)P + off) = (int4){(int)wpat, (int)wpat, (int)wpat, (int)wpat};
        return;
    }
    if (blk < CVT_BLOCKS + PF_BLOCKS + MZ_BLOCKS) {   // ---- zero M ----
        size_t off = ((size_t)(blk - CVT_BLOCKS - PF_BLOCKS) * 256 + threadIdx.x) * 16;
        *(int4*)(M + off) = (int4){0, 0, 0, 0};
        return;
    }
    if (blk < CVT_BLOCKS + PF_BLOCKS + MZ_BLOCKS + RS_BLOCKS) {  // ---- rs fill ----
        int i = (blk - CVT_BLOCKS - PF_BLOCKS - MZ_BLOCKS) * 256 + threadIdx.x;
        rs[i] = (float)LK * score_of(0);
        if (i == 0) *nfix = 0u;
        return;
    }
    // ---- signature branch: 2 token-sets per block ----
    int sb = blk - (CVT_BLOCKS + PF_BLOCKS + MZ_BLOCKS + RS_BLOCKS);  // 0..4095
    int half = threadIdx.x >> 7, k = threadIdx.x & 127;
    int row = sb * 2 + half;
    const int* ts = (row < NB * LQ) ? ts_q : ts_k;
    unsigned* sig = (row < NB * LQ) ? sig_q : sig_k;
    int idx = row & (NB * LQ - 1);
    unsigned long long a  = (unsigned)ha[k];
    unsigned long long bb = (unsigned)hb[k];
    __shared__ int ids[2][S_SET];
    if (k < S_SET) ids[half][k] = ts[idx * S_SET + k];
    __syncthreads();
    unsigned mn = 0xFFFFFFFFu;
    #pragma unroll
    for (int s = 0; s < S_SET; s++) {
        unsigned long long x = a * (unsigned long long)(unsigned)ids[half][s] + bb;
        x = (x & PRIME) + (x >> 31);      // 2^31 == 1 (mod 2^31-1)
        x = (x & PRIME) + (x >> 31);
        unsigned r = (unsigned)x;
        if (r >= PRIME) r -= PRIME;
        mn = (r < mn) ? r : mn;
    }
    sig[idx * K_HASH + k] = mn;
}

// ---------------------------------------------------------------------------
// 2) joing1: sparse equality join (exact) || GEMM1 (Vproj = Vb@Wvb^T + bv).
//    Join block = (b, 4-column group): int4 loads give 4x line efficiency on
//    the stride-512B column reads; 4 sequential rounds share one LDS table.
//    First-touch (q,j) pairs are appended to fixlist (capacity = worst case).
//    Role interleave 1-in-5 spreads the 128 join blocks across CUs (R12:
//    CU = f(blk mod 256)), so every CU keeps MFMA work co-resident (m114).
// ---------------------------------------------------------------------------
union JSmem {
    struct { unsigned keys[2048]; ushort_t vals[2048]; } j;   // 12 KB
    struct { ushort_t As[2][64 * 32]; ushort_t Bs[2][64 * 32]; } g; // 16 KB
};

static __device__ __forceinline__ unsigned vc4(int4 v, int c) {
    return (unsigned)(c == 0 ? v.x : c == 1 ? v.y : c == 2 ? v.z : v.w);
}

__global__ __launch_bounds__(256) void joing1_kernel(
        const unsigned* __restrict__ sig_q, const unsigned* __restrict__ sig_k,
        uint8_t* __restrict__ M, unsigned* __restrict__ fixlist,
        unsigned* __restrict__ nfix,
        const ushort_t* __restrict__ Wvb, const ushort_t* __restrict__ Vb,
        ushort_t* __restrict__ Vproj, const float* __restrict__ bv) {
    __shared__ JSmem sm;
    int blk = blockIdx.x, tid = threadIdx.x;
    int r5 = blk % 5;
    if (r5 < 4) {                         // ---- GEMM1 tile: Vproj (4096x512) ----
        int t = (blk / 5) * 4 + r5;       // 0..511
        gemm64_dev<0, EPI_COLBIAS>(Vb, Wvb, Vproj, bv, nullptr,
                                   EDIM, EDIM, EDIM, EDIM,
                                   (t >> 3) * 64, (t & 7) * 64,
                                   sm.g.As[0], sm.g.Bs[0], tid);
        return;
    }
    // ---- join block: batch b, hash columns kg*4 .. kg*4+3 ----
    int jt = blk / 5;                     // 0..127
    int b = jt >> 5, kg = jt & 31;
    const int4* skb = (const int4*)(sig_k + (size_t)b * LK * K_HASH + kg * 4);
    const int4* sqb = (const int4*)(sig_q + (size_t)b * LQ * K_HASH + kg * 4);
    int4 kv[4], qv[4];
    #pragma unroll
    for (int u = 0; u < 4; u++) {
        int row = u * 256 + tid;
        kv[u] = skb[(size_t)row * (K_HASH / 4)];
        qv[u] = sqb[(size_t)row * (K_HASH / 4)];
    }
    uint8_t* Mb = M + ((size_t)b << 20);
    #pragma unroll
    for (int c = 0; c < 4; c++) {
        __syncthreads();                  // previous round's probes done
        for (int i = tid; i < 2048; i += 256) sm.j.keys[i] = 0xFFFFFFFFu;
        __syncthreads();
        // insert all 1024 k-column values (dups as separate entries)
        #pragma unroll
        for (int u = 0; u < 4; u++) {
            int j = u * 256 + tid;
            unsigned vv = vc4(kv[u], c);
            unsigned h = (vv * 2654435761u) >> 21;       // [0,2048)
            while (true) {
                unsigned prev = atomicCAS(&sm.j.keys[h], 0xFFFFFFFFu, vv);
                if (prev == 0xFFFFFFFFu) { sm.j.vals[h] = (ushort_t)j; break; }
                h = (h + 1) & 2047;
            }
        }
        __syncthreads();
        // probe with the 1024 q-column values
        #pragma unroll
        for (int u = 0; u < 4; u++) {
            int q = u * 256 + tid;
            unsigned vv = vc4(qv[u], c);
            unsigned h = (vv * 2654435761u) >> 21, kk;
            while ((kk = sm.j.keys[h]) != 0xFFFFFFFFu) {
                if (kk == vv) {
                    unsigned ix = ((unsigned)q << 10) + sm.j.vals[h];
                    unsigned sh = (ix & 3u) * 8;
                    unsigned old = atomicAdd((unsigned*)(Mb + (ix & ~3u)), 1u << sh);
                    if (((old >> sh) & 0xFFu) == 0u) {   // first touch -> append
                        unsigned slot = atomicAdd(nfix, 1u);
                        if (slot < (unsigned)FIX_CAP)
                            fixlist[slot] = ((unsigned)b << 20) | ix;
                    }
                }
                h = (h + 1) & 2047;
            }
        }
    }
}

// ---------------------------------------------------------------------------
// 3) g1bfix: W2t = Wob @ Vproj^T (512x4096)  ||  sparse fixup of P and rs at
//    the first-touched (b,q,j) pairs (M holds exact final counts).
// ---------------------------------------------------------------------------
__global__ __launch_bounds__(256) void g1bfix_kernel(
        const ushort_t* __restrict__ Wob, const ushort_t* __restrict__ Vproj,
        ushort_t* __restrict__ W2t,
        const uint8_t* __restrict__ M, const unsigned* __restrict__ fixlist,
        const unsigned* __restrict__ nfix,
        ushort_t* __restrict__ P, float* __restrict__ rs) {
    __shared__ ushort_t As[2][64 * 32], Bs[2][64 * 32];
    int blk = blockIdx.x, tid = threadIdx.x;
    if (blk < 512) {                      // ---- GEMM: W2t tile ----
        gemm64_dev<0, EPI_NONE>(Wob, Vproj, W2t, nullptr, nullptr,
                                EDIM, EDIM, NB * LK, EDIM,
                                (blk >> 6) * 64, (blk & 63) * 64,
                                As[0], Bs[0], tid);
        return;
    }
    // ---- fixup role: 64 blocks grid-stride over the match list ----
    unsigned n = *nfix;
    if (n > (unsigned)FIX_CAP) n = FIX_CAP;
    float p0 = score_of(0);
    for (unsigned i = (unsigned)(blk - 512) * 256 + tid; i < n; i += 64 * 256) {
        unsigned e = fixlist[i];
        int b = e >> 20;
        unsigned ix = e & 0xFFFFFu;
        int m = M[((size_t)b << 20) + ix];
        float p = score_of(m);
        P[((size_t)b << 20) + ix] = f2bf(p);
        atomicAdd(&rs[(b << 10) + (ix >> 10)], p - p0);
    }
}

// ---------------------------------------------------------------------------
// 4) final BT-GEMM (z-batched): out = (P @ W2t^T)/rs + bo, f32 out.
// ---------------------------------------------------------------------------
template<int OUTF32, int MODE>
__global__ __launch_bounds__(256) void btgemm_kernel(
        const ushort_t* __restrict__ A, const ushort_t* __restrict__ B,
        void* __restrict__ C,
        const float* __restrict__ bias, const float* __restrict__ scale,
        int lda, int ldb, int ldc, int Kd,
        long long sA, long long sB, long long sC, long long sS) {
    __shared__ ushort_t As[2][64 * 32], Bs[2][64 * 32];
    int z = blockIdx.z;
    gemm64_dev<OUTF32, MODE>(
        A + (size_t)z * sA, B + (size_t)z * sB,
        (char*)C + (size_t)z * sC * (OUTF32 ? 4 : 2),
        bias, scale + (size_t)z * sS,
        lda, ldb, ldc, Kd, blockIdx.y * 64, blockIdx.x * 64,
        As[0], Bs[0], threadIdx.x);
}

// ---------------------------------------------------------------------------
extern "C" void kernel_launch(void* const* d_in, const int* in_sizes, int n_in,
                              void* d_out, int out_size, void* d_ws, size_t ws_size,
                              hipStream_t stream) {
    // inputs: 0 query 1 key 2 value 3 ts_q 4 ts_k 5 ha 6 hb 7 Wq 8 bq 9 Wk 10 bk
    //         11 Wv 12 bv 13 Wo 14 bo   (q/k projections are dead code)
    const float* value = (const float*)d_in[2];
    const int* tsq = (const int*)d_in[3];
    const int* tsk = (const int*)d_in[4];
    const int* ha  = (const int*)d_in[5];
    const int* hb  = (const int*)d_in[6];
    const float* Wv = (const float*)d_in[11];
    const float* bv = (const float*)d_in[12];
    const float* Wo = (const float*)d_in[13];
    const float* bo = (const float*)d_in[14];
    float* out = (float*)d_out;

    char* ws = (char*)d_ws;
    unsigned* sigq  = (unsigned*)(ws);                               // 2 MB
    unsigned* sigk  = (unsigned*)(ws + (2ull << 20));                // 2 MB
    uint8_t*  M     = (uint8_t*)(ws + (4ull << 20));                 // 4 MB
    ushort_t* P     = (ushort_t*)(ws + (8ull << 20));                // 8 MB
    float*    rs    = (float*)(ws + (16ull << 20));                  // 16 KB
    unsigned* nfix  = (unsigned*)(ws + (16ull << 20) + (32ull << 10)); // 4 B
    unsigned* fixl  = (unsigned*)(ws + (17ull << 20));               // 16 MB
    ushort_t* Vproj = (ushort_t*)(ws + (33ull << 20));               // 4 MB [4096 x 512]
    ushort_t* W2t   = (ushort_t*)(ws + (37ull << 20));               // 4 MB [512 x 4096]
    ushort_t* Vb    = (ushort_t*)(ws + (41ull << 20));               // 4 MB [4096 x 512]
    ushort_t* Wvb   = (ushort_t*)(ws + (45ull << 20));               // 512 KB
    ushort_t* Wob   = (ushort_t*)(ws + (45ull << 20) + (512ull << 10)); // 512 KB

    // 1) converts + signatures + P prefill + M zero + rs fill + nfix zero
    prep_kernel<<<PREP_GRID, 256, 0, stream>>>(
        value, Wv, Wo, Vb, Wvb, Wob, tsq, tsk, ha, hb, sigq, sigk,
        M, P, rs, nfix);

    // 2) sparse join (128 blocks, 1-in-5) || GEMM1 Vproj (512 blocks)
    joing1_kernel<<<640, 256, 0, stream>>>(
        sigq, sigk, M, fixl, nfix, Wvb, Vb, Vproj, bv);

    // 3) W2t = Wob @ Vproj^T  ||  sparse P/rs fixup
    g1bfix_kernel<<<576, 256, 0, stream>>>(
        Wob, Vproj, W2t, M, fixl, nfix, P, rs);

    // 4) out[b,q,n] = (sum_j P[b,q,j] * W2t[n, b*1024+j]) / rs[b,q] + bo[n]
    btgemm_kernel<1, EPI_DIVBIAS><<<dim3(EDIM / 64, LQ / 64, NB), 256, 0, stream>>>(
        P, W2t, out, bo, rs,
        LK, NB * LK, EDIM, LK,
        (long long)LQ * LK, (long long)LK, (long long)LQ * EDIM, (long long)LQ);
}

// Round 7
// 183.322 us; speedup vs baseline: 1.1633x; 1.1633x over previous
//
#include <hip/hip_runtime.h>
#include <hip/hip_bf16.h>
#include <stdint.h>

// Problem constants (fixed by setup_inputs)
#define PRIME 2147483647u
#define GAMMA 0.3f
#define K_HASH 128
#define S_SET 8
#define NB 4
#define LQ 1024
#define LK 1024
#define EDIM 512
#define FIX_CAP (NB * LQ * LK)   // exact worst case: every pair touched once

typedef unsigned short ushort_t;
typedef __attribute__((ext_vector_type(8))) short short8;
typedef __attribute__((ext_vector_type(4))) float f32x4;

static __device__ __forceinline__ unsigned short f2bf(float f) {
    unsigned u = __builtin_bit_cast(unsigned, f);
    u += 0x7FFFu + ((u >> 16) & 1u);   // RNE (no NaN in this problem)
    return (unsigned short)(u >> 16);
}

// async global->LDS, 16B per lane; LDS dst must be lane-contiguous.
static __device__ __forceinline__ void glds16(const void* g, void* l) {
    __builtin_amdgcn_global_load_lds(
        (const __attribute__((address_space(1))) unsigned int*)g,
        (__attribute__((address_space(3))) unsigned int*)l, 16, 0, 0);
}

#define SWZ(r) ((((r) >> 2) & 3) ^ ((r) & 3))

// score(m) = exp(exp(-GAMMA * 2S * (K-m)/(K+m))), m = matched hash slots
static __device__ __forceinline__ float score_of(int m) {
    float r = (float)(K_HASH - m) / (float)(K_HASH + m);
    return expf(expf(-GAMMA * (2.0f * S_SET) * r));
}

// ---------------------------------------------------------------------------
// 64x64-tile bf16 BT-GEMM device fn: C=A@B^T (+epilogue), f32 accum,
// 4 waves x 32x32, glds width-16, XOR-swizzled LDS, double-buffered.
// ---------------------------------------------------------------------------
#define EPI_ROWBIAS  0   // v += bias[gm]
#define EPI_COLBIAS  2   // v += bias[gn]
#define EPI_NONE     3   // v unchanged
#define EPI_DIVBIAS  4   // v = v/scale[gm] + bias[gn]

template<int OUTF32, int MODE>
static __device__ void gemm64_dev(
        const ushort_t* __restrict__ A, const ushort_t* __restrict__ B,
        void* __restrict__ C,
        const float* __restrict__ bias, const float* __restrict__ scale,
        int lda, int ldb, int ldc, int Kd, int m0, int n0,
        ushort_t* AsBase, ushort_t* BsBase, int tid) {
    ushort_t (*As)[64 * 32] = (ushort_t (*)[64 * 32])AsBase;
    ushort_t (*Bs)[64 * 32] = (ushort_t (*)[64 * 32])BsBase;
    int w = tid >> 6, lane = tid & 63;
    int wm = (w & 1) * 32, wn = (w >> 1) * 32;
    int mrow = lane & 15, kg = lane >> 4;

    int r = tid >> 2, c = (tid & 3) ^ SWZ(r);
    const ushort_t* pa = A + (size_t)(m0 + r) * lda + c * 8;
    const ushort_t* pb = B + (size_t)(n0 + r) * ldb + c * 8;

    int aoff[2], boff[2];
    #pragma unroll
    for (int s = 0; s < 2; s++) {
        int Ra = wm + s * 16 + mrow;
        aoff[s] = Ra * 32 + (kg ^ SWZ(Ra)) * 8;
        int Rb = wn + s * 16 + mrow;
        boff[s] = Rb * 32 + (kg ^ SWZ(Rb)) * 8;
    }

    f32x4 acc[2][2] = {};
    int nK = Kd >> 5;
    glds16(pa, &As[0][tid * 8]);
    glds16(pb, &Bs[0][tid * 8]);
    for (int i = 0; i < nK; i++) {
        __syncthreads();
        int cur = i & 1, nxt = cur ^ 1;
        if (i + 1 < nK) {
            int k0 = (i + 1) << 5;
            glds16(pa + k0, &As[nxt][tid * 8]);
            glds16(pb + k0, &Bs[nxt][tid * 8]);
        }
        short8 af[2], bh[2];
        #pragma unroll
        for (int s = 0; s < 2; s++) {
            af[s] = *(const short8*)&As[cur][aoff[s]];
            bh[s] = *(const short8*)&Bs[cur][boff[s]];
        }
        #pragma unroll
        for (int ii = 0; ii < 2; ii++)
            #pragma unroll
            for (int jj = 0; jj < 2; jj++)
                acc[ii][jj] = __builtin_amdgcn_mfma_f32_16x16x32_bf16(
                                  af[ii], bh[jj], acc[ii][jj], 0, 0, 0);
    }

    int col = lane & 15, rbase = (lane >> 4) * 4;
    #pragma unroll
    for (int ii = 0; ii < 2; ii++) {
        #pragma unroll
        for (int jj = 0; jj < 2; jj++) {
            #pragma unroll
            for (int rr = 0; rr < 4; rr++) {
                int gm = m0 + wm + ii * 16 + rbase + rr;
                int gn = n0 + wn + jj * 16 + col;
                float v = acc[ii][jj][rr];
                if (MODE == EPI_ROWBIAS)      v += bias[gm];
                else if (MODE == EPI_COLBIAS) v += bias[gn];
                else if (MODE == EPI_DIVBIAS) v = v / scale[gm] + bias[gn];
                size_t cix = (size_t)gm * ldc + gn;
                if (OUTF32) ((float*)C)[cix] = v;
                else        ((ushort_t*)C)[cix] = f2bf(v);
            }
        }
    }
}

// ---------------------------------------------------------------------------
// 1) prep: f32->bf16 converts (value/Wv/Wo) + column-major MinHash signatures
//    sigT[k][4096] (u32, exact; LDS tile-transpose -> coalesced writes)
//    + P prefill with bf16(score(0)) + M zero + rs fill + nfix zero.
// ---------------------------------------------------------------------------
#define CVT_N0 (NB * LK * EDIM)
#define CVT_N1 (EDIM * EDIM)
#define CVT_N2 (EDIM * EDIM)
#define CVT_BLOCKS ((CVT_N0 + CVT_N1 + CVT_N2) / (256 * 8))   // 1280
#define PF_BLOCKS 2048     // 8 MB P / 4 KB
#define MZ_BLOCKS 1024     // 4 MB M / 4 KB
#define RS_BLOCKS 16       // 4096 f32
#define SIGT_BLOCKS 128    // 8192 rows / 64 rows per block
#define PREP_GRID (CVT_BLOCKS + PF_BLOCKS + MZ_BLOCKS + RS_BLOCKS + SIGT_BLOCKS)

__global__ __launch_bounds__(256) void prep_kernel(
        const float* __restrict__ v, const float* __restrict__ wv,
        const float* __restrict__ wo,
        ushort_t* __restrict__ vb, ushort_t* __restrict__ wvb,
        ushort_t* __restrict__ wob,
        const int* __restrict__ ts_q, const int* __restrict__ ts_k,
        const int* __restrict__ ha, const int* __restrict__ hb,
        unsigned* __restrict__ sigTq, unsigned* __restrict__ sigTk,
        uint8_t* __restrict__ M, ushort_t* __restrict__ P,
        float* __restrict__ rs, unsigned* __restrict__ nfix) {
    __shared__ unsigned tile[128 * 65];   // pitch-65: write banks (k+r)%32, 2-way
    __shared__ int ids_s[64 * S_SET];
    int blk = blockIdx.x, tid = threadIdx.x;
    if (blk < CVT_BLOCKS) {               // ---- convert branch ----
        size_t i = ((size_t)blk * 256 + tid) * 8;
        const float* src; ushort_t* dst; size_t off;
        if (i < CVT_N0)                { src = v;  dst = vb;  off = i; }
        else if (i < CVT_N0 + CVT_N1)  { src = wv; dst = wvb; off = i - CVT_N0; }
        else                           { src = wo; dst = wob; off = i - CVT_N0 - CVT_N1; }
        float4 a = *(const float4*)(src + off);
        float4 b = *(const float4*)(src + off + 4);
        ushort4 o0, o1;
        o0.x = f2bf(a.x); o0.y = f2bf(a.y); o0.z = f2bf(a.z); o0.w = f2bf(a.w);
        o1.x = f2bf(b.x); o1.y = f2bf(b.y); o1.z = f2bf(b.z); o1.w = f2bf(b.w);
        *(ushort4*)(dst + off)     = o0;
        *(ushort4*)(dst + off + 4) = o1;
        return;
    }
    if (blk < CVT_BLOCKS + PF_BLOCKS) {   // ---- P prefill: bf16(score(0)) ----
        unsigned short pb = f2bf(score_of(0));
        unsigned wpat = (unsigned)pb | ((unsigned)pb << 16);
        size_t off = ((size_t)(blk - CVT_BLOCKS) * 256 + tid) * 16;
        *(int4*)((char*)P + off) = (int4){(int)wpat, (int)wpat, (int)wpat, (int)wpat};
        return;
    }
    if (blk < CVT_BLOCKS + PF_BLOCKS + MZ_BLOCKS) {   // ---- zero M ----
        size_t off = ((size_t)(blk - CVT_BLOCKS - PF_BLOCKS) * 256 + tid) * 16;
        *(int4*)(M + off) = (int4){0, 0, 0, 0};
        return;
    }
    if (blk < CVT_BLOCKS + PF_BLOCKS + MZ_BLOCKS + RS_BLOCKS) {  // ---- rs fill ----
        int i = (blk - CVT_BLOCKS - PF_BLOCKS - MZ_BLOCKS) * 256 + tid;
        rs[i] = (float)LK * score_of(0);
        if (i == 0) *nfix = 0u;
        return;
    }
    // ---- sigT branch: 64 rows x all 128 k, written column-major ----
    int sb = blk - (CVT_BLOCKS + PF_BLOCKS + MZ_BLOCKS + RS_BLOCKS);  // 0..127
    int r0 = sb * 64;                     // global row 0..8191 (q then k)
    const int* ts = (r0 < NB * LQ) ? ts_q : ts_k;
    unsigned* sigT = (r0 < NB * LQ) ? sigTq : sigTk;
    int base = r0 & (NB * LQ - 1);        // row offset within source
    // load 64 rows x 8 ids = 512 ints, coalesced
    ((int2*)ids_s)[tid] = ((const int2*)(ts + (size_t)base * S_SET))[tid];
    __syncthreads();
    int kt = tid & 127, rt = tid >> 7;
    unsigned long long a  = (unsigned)ha[kt];
    unsigned long long bb = (unsigned)hb[kt];
    for (int r = rt; r < 64; r += 2) {
        unsigned mn = 0xFFFFFFFFu;
        #pragma unroll
        for (int s = 0; s < S_SET; s++) {
            unsigned long long x =
                a * (unsigned long long)(unsigned)ids_s[r * S_SET + s] + bb;
            x = (x & PRIME) + (x >> 31);  // 2^31 == 1 (mod 2^31-1)
            x = (x & PRIME) + (x >> 31);
            unsigned rr = (unsigned)x;
            if (rr >= PRIME) rr -= PRIME;
            mn = (rr < mn) ? rr : mn;
        }
        tile[kt * 65 + r] = mn;
    }
    __syncthreads();
    // write out: each 64-lane group writes one k's 64 consecutive rows (256B)
    #pragma unroll
    for (int ch = 0; ch < 32; ch++) {
        int idx = ch * 256 + tid;
        int k = idx >> 6, r = idx & 63;
        sigT[(size_t)k * (NB * LQ) + base + r] = tile[k * 65 + r];
    }
}

// ---------------------------------------------------------------------------
// 2) joing1: sparse equality join (exact) || GEMM1 (Vproj = Vb@Wvb^T + bv).
//    Join block = one (b,k): loads two fully-contiguous 4 KB sigT columns
//    (uint4/thread), hashes the 1024 k-values into a 2048-slot LDS table
//    (dups as separate entries -> exact multiplicity), probes with the 1024
//    q-values, emits byte atomicAdds into M + first-touch fixlist appends.
//    Role = 256-block groups (R12: CU = f(blk mod 256)): join,gemm,join,gemm
//    -> every CU holds 2 join + 2 GEMM blocks (m114 MFMA/VALU co-schedule).
// ---------------------------------------------------------------------------
union JSmem {
    struct { unsigned keys[2048]; ushort_t vals[2048]; } j;   // 12 KB
    struct { ushort_t As[2][64 * 32]; ushort_t Bs[2][64 * 32]; } g; // 16 KB
};

__global__ __launch_bounds__(256) void joing1_kernel(
        const unsigned* __restrict__ sigTq, const unsigned* __restrict__ sigTk,
        uint8_t* __restrict__ M, unsigned* __restrict__ fixlist,
        unsigned* __restrict__ nfix,
        const ushort_t* __restrict__ Wvb, const ushort_t* __restrict__ Vb,
        ushort_t* __restrict__ Vproj, const float* __restrict__ bv) {
    __shared__ JSmem sm;
    int blk = blockIdx.x, tid = threadIdx.x;
    int grp = blk >> 8;                   // 0..3: join, gemm, join, gemm
    int t = (grp >> 1) * 256 + (blk & 255);   // role-local id 0..511
    if (grp & 1) {                        // ---- GEMM1 tile: Vproj (4096x512) ----
        gemm64_dev<0, EPI_COLBIAS>(Vb, Wvb, Vproj, bv, nullptr,
                                   EDIM, EDIM, EDIM, EDIM,
                                   (t >> 3) * 64, (t & 7) * 64,
                                   sm.g.As[0], sm.g.Bs[0], tid);
        return;
    }
    // ---- join block: batch b, hash column k ----
    int b = t >> 7, k = t & 127;
    const unsigned* kc = sigTk + (size_t)k * (NB * LK) + b * LK;
    const unsigned* qc = sigTq + (size_t)k * (NB * LQ) + b * LQ;
    uint4 kv = ((const uint4*)kc)[tid];   // j = tid*4 .. tid*4+3
    uint4 qv = ((const uint4*)qc)[tid];
    #pragma unroll
    for (int i = 0; i < 8; i++) sm.j.keys[i * 256 + tid] = 0xFFFFFFFFu;
    __syncthreads();
    // insert all 1024 k-column values (dups as separate entries)
    unsigned kvv[4] = {kv.x, kv.y, kv.z, kv.w};
    #pragma unroll
    for (int e = 0; e < 4; e++) {
        unsigned vv = kvv[e];
        unsigned h = (vv * 2654435761u) >> 21;       // [0,2048)
        while (true) {
            unsigned prev = atomicCAS(&sm.j.keys[h], 0xFFFFFFFFu, vv);
            if (prev == 0xFFFFFFFFu) { sm.j.vals[h] = (ushort_t)(tid * 4 + e); break; }
            h = (h + 1) & 2047;
        }
    }
    __syncthreads();
    // probe with the 1024 q-column values
    uint8_t* Mb = M + ((size_t)b << 20);
    unsigned qvv[4] = {qv.x, qv.y, qv.z, qv.w};
    #pragma unroll
    for (int e = 0; e < 4; e++) {
        unsigned vv = qvv[e];
        unsigned h = (vv * 2654435761u) >> 21, kk;
        while ((kk = sm.j.keys[h]) != 0xFFFFFFFFu) {
            if (kk == vv) {
                unsigned ix = ((unsigned)(tid * 4 + e) << 10) + sm.j.vals[h];
                unsigned sh = (ix & 3u) * 8;
                unsigned old = atomicAdd((unsigned*)(Mb + (ix & ~3u)), 1u << sh);
                if (((old >> sh) & 0xFFu) == 0u) {   // first touch -> append
                    unsigned slot = atomicAdd(nfix, 1u);
                    if (slot < (unsigned)FIX_CAP)
                        fixlist[slot] = ((unsigned)b << 20) | ix;
                }
            }
            h = (h + 1) & 2047;
        }
    }
}

// ---------------------------------------------------------------------------
// 3) g1bfix: W2t = Wob @ Vproj^T (512x4096)  ||  sparse fixup of P and rs at
//    the first-touched (b,q,j) pairs (M holds exact final counts).
// ---------------------------------------------------------------------------
__global__ __launch_bounds__(256) void g1bfix_kernel(
        const ushort_t* __restrict__ Wob, const ushort_t* __restrict__ Vproj,
        ushort_t* __restrict__ W2t,
        const uint8_t* __restrict__ M, const unsigned* __restrict__ fixlist,
        const unsigned* __restrict__ nfix,
        ushort_t* __restrict__ P, float* __restrict__ rs) {
    __shared__ ushort_t As[2][64 * 32], Bs[2][64 * 32];
    int blk = blockIdx.x, tid = threadIdx.x;
    if (blk < 512) {                      // ---- GEMM: W2t tile ----
        gemm64_dev<0, EPI_NONE>(Wob, Vproj, W2t, nullptr, nullptr,
                                EDIM, EDIM, NB * LK, EDIM,
                                (blk >> 6) * 64, (blk & 63) * 64,
                                As[0], Bs[0], tid);
        return;
    }
    // ---- fixup role: 64 blocks grid-stride over the match list ----
    unsigned n = *nfix;
    if (n > (unsigned)FIX_CAP) n = FIX_CAP;
    float p0 = score_of(0);
    for (unsigned i = (unsigned)(blk - 512) * 256 + tid; i < n; i += 64 * 256) {
        unsigned e = fixlist[i];
        int b = e >> 20;
        unsigned ix = e & 0xFFFFFu;
        int m = M[((size_t)b << 20) + ix];
        float p = score_of(m);
        P[((size_t)b << 20) + ix] = f2bf(p);
        atomicAdd(&rs[(b << 10) + (ix >> 10)], p - p0);
    }
}

// ---------------------------------------------------------------------------
// 4) final BT-GEMM (z-batched): out = (P @ W2t^T)/rs + bo, f32 out.
// ---------------------------------------------------------------------------
template<int OUTF32, int MODE>
__global__ __launch_bounds__(256) void btgemm_kernel(
        const ushort_t* __restrict__ A, const ushort_t* __restrict__ B,
        void* __restrict__ C,
        const float* __restrict__ bias, const float* __restrict__ scale,
        int lda, int ldb, int ldc, int Kd,
        long long sA, long long sB, long long sC, long long sS) {
    __shared__ ushort_t As[2][64 * 32], Bs[2][64 * 32];
    int z = blockIdx.z;
    gemm64_dev<OUTF32, MODE>(
        A + (size_t)z * sA, B + (size_t)z * sB,
        (char*)C + (size_t)z * sC * (OUTF32 ? 4 : 2),
        bias, scale + (size_t)z * sS,
        lda, ldb, ldc, Kd, blockIdx.y * 64, blockIdx.x * 64,
        As[0], Bs[0], threadIdx.x);
}

// ---------------------------------------------------------------------------
extern "C" void kernel_launch(void* const* d_in, const int* in_sizes, int n_in,
                              void* d_out, int out_size, void* d_ws, size_t ws_size,
                              hipStream_t stream) {
    // inputs: 0 query 1 key 2 value 3 ts_q 4 ts_k 5 ha 6 hb 7 Wq 8 bq 9 Wk 10 bk
    //         11 Wv 12 bv 13 Wo 14 bo   (q/k projections are dead code)
    const float* value = (const float*)d_in[2];
    const int* tsq = (const int*)d_in[3];
    const int* tsk = (const int*)d_in[4];
    const int* ha  = (const int*)d_in[5];
    const int* hb  = (const int*)d_in[6];
    const float* Wv = (const float*)d_in[11];
    const float* bv = (const float*)d_in[12];
    const float* Wo = (const float*)d_in[13];
    const float* bo = (const float*)d_in[14];
    float* out = (float*)d_out;

    char* ws = (char*)d_ws;
    unsigned* sigTq = (unsigned*)(ws);                               // 2 MB [128][4096]
    unsigned* sigTk = (unsigned*)(ws + (2ull << 20));                // 2 MB [128][4096]
    uint8_t*  M     = (uint8_t*)(ws + (4ull << 20));                 // 4 MB
    ushort_t* P     = (ushort_t*)(ws + (8ull << 20));                // 8 MB
    float*    rs    = (float*)(ws + (16ull << 20));                  // 16 KB
    unsigned* nfix  = (unsigned*)(ws + (16ull << 20) + (32ull << 10)); // 4 B
    unsigned* fixl  = (unsigned*)(ws + (17ull << 20));               // 16 MB
    ushort_t* Vproj = (ushort_t*)(ws + (33ull << 20));               // 4 MB [4096 x 512]
    ushort_t* W2t   = (ushort_t*)(ws + (37ull << 20));               // 4 MB [512 x 4096]
    ushort_t* Vb    = (ushort_t*)(ws + (41ull << 20));               // 4 MB [4096 x 512]
    ushort_t* Wvb   = (ushort_t*)(ws + (45ull << 20));               // 512 KB
    ushort_t* Wob   = (ushort_t*)(ws + (45ull << 20) + (512ull << 10)); // 512 KB

    // 1) converts + sigT (column-major) + P prefill + M zero + rs fill
    prep_kernel<<<PREP_GRID, 256, 0, stream>>>(
        value, Wv, Wo, Vb, Wvb, Wob, tsq, tsk, ha, hb, sigTq, sigTk,
        M, P, rs, nfix);

    // 2) sparse join (512 blocks) || GEMM1 Vproj (512 blocks), 2+2 per CU
    joing1_kernel<<<1024, 256, 0, stream>>>(
        sigTq, sigTk, M, fixl, nfix, Wvb, Vb, Vproj, bv);

    // 3) W2t = Wob @ Vproj^T  ||  sparse P/rs fixup
    g1bfix_kernel<<<576, 256, 0, stream>>>(
        Wob, Vproj, W2t, M, fixl, nfix, P, rs);

    // 4) out[b,q,n] = (sum_j P[b,q,j] * W2t[n, b*1024+j]) / rs[b,q] + bo[n]
    btgemm_kernel<1, EPI_DIVBIAS><<<dim3(EDIM / 64, LQ / 64, NB), 256, 0, stream>>>(
        P, W2t, out, bo, rs,
        LK, NB * LK, EDIM, LK,
        (long long)LQ * LK, (long long)LK, (long long)LQ * EDIM, (long long)LQ);
}

// Round 8
// 177.564 us; speedup vs baseline: 1.2010x; 1.0324x over previous
//
#include <hip/hip_runtime.h>
#include <hip/hip_bf16.h>
#include <stdint.h>

// Problem constants (fixed by setup_inputs)
#define PRIME 2147483647u
#define GAMMA 0.3f
#define K_HASH 128
#define S_SET 8
#define NB 4
#define LQ 1024
#define LK 1024
#define EDIM 512

typedef unsigned short ushort_t;
typedef __attribute__((ext_vector_type(8))) short short8;
typedef __attribute__((ext_vector_type(4))) float f32x4;

static __device__ __forceinline__ unsigned short f2bf(float f) {
    unsigned u = __builtin_bit_cast(unsigned, f);
    u += 0x7FFFu + ((u >> 16) & 1u);   // RNE (no NaN in this problem)
    return (unsigned short)(u >> 16);
}

// async global->LDS, 16B per lane; LDS dst must be lane-contiguous.
static __device__ __forceinline__ void glds16(const void* g, void* l) {
    __builtin_amdgcn_global_load_lds(
        (const __attribute__((address_space(1))) unsigned int*)g,
        (__attribute__((address_space(3))) unsigned int*)l, 16, 0, 0);
}

#define SWZ(r) ((((r) >> 2) & 3) ^ ((r) & 3))

// score(m) = exp(exp(-GAMMA * 2S * (K-m)/(K+m))), m = matched hash slots
static __device__ __forceinline__ float score_of(int m) {
    float r = (float)(K_HASH - m) / (float)(K_HASH + m);
    return expf(expf(-GAMMA * (2.0f * S_SET) * r));
}

// ---------------------------------------------------------------------------
// 64x64-tile bf16 BT-GEMM device fn: C=A@B^T, f32 accum, 4 waves x 32x32,
// glds width-16, XOR-swizzled LDS, double-buffered.
// ---------------------------------------------------------------------------
#define EPI_NONE 3

template<int OUTF32, int MODE>
static __device__ void gemm64_dev(
        const ushort_t* __restrict__ A, const ushort_t* __restrict__ B,
        void* __restrict__ C,
        int lda, int ldb, int ldc, int Kd, int m0, int n0,
        ushort_t* AsBase, ushort_t* BsBase, int tid) {
    ushort_t (*As)[64 * 32] = (ushort_t (*)[64 * 32])AsBase;
    ushort_t (*Bs)[64 * 32] = (ushort_t (*)[64 * 32])BsBase;
    int w = tid >> 6, lane = tid & 63;
    int wm = (w & 1) * 32, wn = (w >> 1) * 32;
    int mrow = lane & 15, kg = lane >> 4;

    int r = tid >> 2, c = (tid & 3) ^ SWZ(r);
    const ushort_t* pa = A + (size_t)(m0 + r) * lda + c * 8;
    const ushort_t* pb = B + (size_t)(n0 + r) * ldb + c * 8;

    int aoff[2], boff[2];
    #pragma unroll
    for (int s = 0; s < 2; s++) {
        int Ra = wm + s * 16 + mrow;
        aoff[s] = Ra * 32 + (kg ^ SWZ(Ra)) * 8;
        int Rb = wn + s * 16 + mrow;
        boff[s] = Rb * 32 + (kg ^ SWZ(Rb)) * 8;
    }

    f32x4 acc[2][2] = {};
    int nK = Kd >> 5;
    glds16(pa, &As[0][tid * 8]);
    glds16(pb, &Bs[0][tid * 8]);
    for (int i = 0; i < nK; i++) {
        __syncthreads();
        int cur = i & 1, nxt = cur ^ 1;
        if (i + 1 < nK) {
            int k0 = (i + 1) << 5;
            glds16(pa + k0, &As[nxt][tid * 8]);
            glds16(pb + k0, &Bs[nxt][tid * 8]);
        }
        short8 af[2], bh[2];
        #pragma unroll
        for (int s = 0; s < 2; s++) {
            af[s] = *(const short8*)&As[cur][aoff[s]];
            bh[s] = *(const short8*)&Bs[cur][boff[s]];
        }
        #pragma unroll
        for (int ii = 0; ii < 2; ii++)
            #pragma unroll
            for (int jj = 0; jj < 2; jj++)
                acc[ii][jj] = __builtin_amdgcn_mfma_f32_16x16x32_bf16(
                                  af[ii], bh[jj], acc[ii][jj], 0, 0, 0);
    }

    int col = lane & 15, rbase = (lane >> 4) * 4;
    #pragma unroll
    for (int ii = 0; ii < 2; ii++) {
        #pragma unroll
        for (int jj = 0; jj < 2; jj++) {
            #pragma unroll
            for (int rr = 0; rr < 4; rr++) {
                int gm = m0 + wm + ii * 16 + rbase + rr;
                int gn = n0 + wn + jj * 16 + col;
                float v = acc[ii][jj][rr];
                size_t cix = (size_t)gm * ldc + gn;
                if (OUTF32) ((float*)C)[cix] = v;
                else        ((ushort_t*)C)[cix] = f2bf(v);
            }
        }
    }
}

// ---------------------------------------------------------------------------
// 1) prep: value->Vb, Wo->Wob (bf16) + Wv->WvT (bf16 transposed, LDS tile)
//    + column-major MinHash signatures sigT[k][4096] (u32, exact)
//    + M zero + vbsum[4][512] (f32 colsums of value) + bob = bo + bv@Wo^T.
// ---------------------------------------------------------------------------
#define CVT_N0 (NB * LK * EDIM)
#define CVT_N1 (EDIM * EDIM)
#define CVT_BLOCKS ((CVT_N0 + CVT_N1) / (256 * 8))   // 1152
#define MZ_BLOCKS 1024     // 4 MB M / 4 KB
#define SIGT_BLOCKS 128    // 8192 rows / 64 rows per block
#define VBS_BLOCKS 16      // 4 b x 4 e-chunks
#define WVT_BLOCKS 64      // 8x8 64x64 transpose tiles
#define BOB_BLOCKS 2
#define PREP_GRID (CVT_BLOCKS + MZ_BLOCKS + SIGT_BLOCKS + VBS_BLOCKS + WVT_BLOCKS + BOB_BLOCKS)

__global__ __launch_bounds__(256) void prep_kernel(
        const float* __restrict__ value, const float* __restrict__ Wv,
        const float* __restrict__ Wo, const float* __restrict__ bv,
        const float* __restrict__ bo,
        ushort_t* __restrict__ Vb, ushort_t* __restrict__ Wob,
        ushort_t* __restrict__ WvT,
        const int* __restrict__ ts_q, const int* __restrict__ ts_k,
        const int* __restrict__ ha, const int* __restrict__ hb,
        unsigned* __restrict__ sigTq, unsigned* __restrict__ sigTk,
        uint8_t* __restrict__ M, float* __restrict__ vbsum,
        float* __restrict__ bob) {
    __shared__ unsigned tile[128 * 65];   // sigT transpose / WvT (ushort view)
    __shared__ int ids_s[64 * S_SET];
    __shared__ float vs[256];
    int blk = blockIdx.x, tid = threadIdx.x;
    if (blk < CVT_BLOCKS) {               // ---- convert branch ----
        size_t i = ((size_t)blk * 256 + tid) * 8;
        const float* src; ushort_t* dst; size_t off;
        if (i < CVT_N0) { src = value; dst = Vb;  off = i; }
        else            { src = Wo;    dst = Wob; off = i - CVT_N0; }
        float4 a = *(const float4*)(src + off);
        float4 b = *(const float4*)(src + off + 4);
        ushort4 o0, o1;
        o0.x = f2bf(a.x); o0.y = f2bf(a.y); o0.z = f2bf(a.z); o0.w = f2bf(a.w);
        o1.x = f2bf(b.x); o1.y = f2bf(b.y); o1.z = f2bf(b.z); o1.w = f2bf(b.w);
        *(ushort4*)(dst + off)     = o0;
        *(ushort4*)(dst + off + 4) = o1;
        return;
    }
    if (blk < CVT_BLOCKS + MZ_BLOCKS) {   // ---- zero M ----
        size_t off = ((size_t)(blk - CVT_BLOCKS) * 256 + tid) * 16;
        *(int4*)(M + off) = (int4){0, 0, 0, 0};
        return;
    }
    if (blk < CVT_BLOCKS + MZ_BLOCKS + SIGT_BLOCKS) {
        // ---- sigT branch: 64 rows x all 128 k, written column-major ----
        int sb = blk - (CVT_BLOCKS + MZ_BLOCKS);   // 0..127
        int r0 = sb * 64;                 // global row 0..8191 (q then k)
        const int* ts = (r0 < NB * LQ) ? ts_q : ts_k;
        unsigned* sigT = (r0 < NB * LQ) ? sigTq : sigTk;
        int base = r0 & (NB * LQ - 1);
        ((int2*)ids_s)[tid] = ((const int2*)(ts + (size_t)base * S_SET))[tid];
        __syncthreads();
        int kt = tid & 127, rt = tid >> 7;
        unsigned long long a  = (unsigned)ha[kt];
        unsigned long long bb = (unsigned)hb[kt];
        for (int r = rt; r < 64; r += 2) {
            unsigned mn = 0xFFFFFFFFu;
            #pragma unroll
            for (int s = 0; s < S_SET; s++) {
                unsigned long long x =
                    a * (unsigned long long)(unsigned)ids_s[r * S_SET + s] + bb;
                x = (x & PRIME) + (x >> 31);  // 2^31 == 1 (mod 2^31-1)
                x = (x & PRIME) + (x >> 31);
                unsigned rr = (unsigned)x;
                if (rr >= PRIME) rr -= PRIME;
                mn = (rr < mn) ? rr : mn;
            }
            tile[kt * 65 + r] = mn;
        }
        __syncthreads();
        #pragma unroll
        for (int ch = 0; ch < 32; ch++) {
            int idx = ch * 256 + tid;
            int k = idx >> 6, r = idx & 63;
            sigT[(size_t)k * (NB * LQ) + base + r] = tile[k * 65 + r];
        }
        return;
    }
    if (blk < CVT_BLOCKS + MZ_BLOCKS + SIGT_BLOCKS + VBS_BLOCKS) {
        // ---- vbsum: f32 column sums of value, per (b, 128-e-chunk) ----
        int vb = blk - (CVT_BLOCKS + MZ_BLOCKS + SIGT_BLOCKS);  // 0..15
        int b = vb >> 2, ch = vb & 3;
        int e = ch * 128 + (tid & 127), half = tid >> 7;
        const float* vp = value + ((size_t)(b * LK) + half * 512) * EDIM + e;
        float s = 0.f;
        for (int j = 0; j < 512; j++) s += vp[(size_t)j * EDIM];
        vs[tid] = s;
        __syncthreads();
        if (tid < 128) vbsum[b * EDIM + ch * 128 + tid] = vs[tid] + vs[tid + 128];
        return;
    }
    if (blk < CVT_BLOCKS + MZ_BLOCKS + SIGT_BLOCKS + VBS_BLOCKS + WVT_BLOCKS) {
        // ---- WvT: 64x64 transpose tiles, WvT[e][e'] = bf16(Wv[e'][e]) ----
        int wt = blk - (CVT_BLOCKS + MZ_BLOCKS + SIGT_BLOCKS + VBS_BLOCKS);
        int r0 = (wt >> 3) * 64, c0 = (wt & 7) * 64;
        ushort_t (*tt)[65] = (ushort_t (*)[65])tile;
        #pragma unroll
        for (int p = 0; p < 16; p++) {
            int idx = p * 256 + tid, r = idx >> 6, c = idx & 63;
            tt[c][r] = f2bf(Wv[(size_t)(r0 + r) * EDIM + c0 + c]);
        }
        __syncthreads();
        #pragma unroll
        for (int p = 0; p < 16; p++) {
            int idx = p * 256 + tid, r = idx >> 6, c = idx & 63;
            WvT[(size_t)(c0 + r) * EDIM + r0 + c] = tt[r][c];
        }
        return;
    }
    // ---- bob = bo + bv @ Wo^T (f32) ----
    int bb = blk - (CVT_BLOCKS + MZ_BLOCKS + SIGT_BLOCKS + VBS_BLOCKS + WVT_BLOCKS);
    int n = bb * 256 + tid;
    const float* worow = Wo + (size_t)n * EDIM;
    float acc = bo[n];
    for (int e = 0; e < EDIM; e++) acc += bv[e] * worow[e];
    bob[n] = acc;
}

// ---------------------------------------------------------------------------
// 2) joing1: sparse equality join (exact, fire-and-forget M atomics, 4-way
//    interleaved hash walks) || Wvo = Wob@WvT^T (64 tiles) || vpsum (8 blks).
//    Join block = one (b,k): two contiguous 4 KB sigT columns; 2048-slot LDS
//    table (dups kept -> exact multiplicity); probes emit byte atomicAdds
//    into M with NO return use (no L2 round-trip on the critical path).
// ---------------------------------------------------------------------------
union JSmem {
    struct { unsigned keys[2048]; ushort_t vals[2048]; } j;   // 12 KB
    struct { ushort_t As[2][64 * 32]; ushort_t Bs[2][64 * 32]; } g; // 16 KB
};

__global__ __launch_bounds__(256) void joing1_kernel(
        const unsigned* __restrict__ sigTq, const unsigned* __restrict__ sigTk,
        uint8_t* __restrict__ M,
        const ushort_t* __restrict__ Wob, const ushort_t* __restrict__ WvT,
        ushort_t* __restrict__ Wvo,
        const float* __restrict__ vbsum, const float* __restrict__ Wv,
        float* __restrict__ vpsum) {
    __shared__ JSmem sm;
    int blk = blockIdx.x, tid = threadIdx.x;
    if (blk >= 512 + 64) {                // ---- vpsum[b,e'] = vbsum[b,:].Wv[e',:] ----
        int vb = blk - 576, b = vb >> 1;
        int ep = (vb & 1) * 256 + tid;
        const float* wvrow = Wv + (size_t)ep * EDIM;
        const float* vbs = vbsum + b * EDIM;
        float acc = 0.f;
        for (int e = 0; e < EDIM; e++) acc += vbs[e] * wvrow[e];
        vpsum[b * EDIM + ep] = acc;
        return;
    }
    if (blk >= 512) {                     // ---- Wvo[n,e] = Wob[n,:].WvT[e,:] ----
        int t = blk - 512;
        gemm64_dev<0, EPI_NONE>(Wob, WvT, Wvo,
                                EDIM, EDIM, EDIM, EDIM,
                                (t >> 3) * 64, (t & 7) * 64,
                                sm.g.As[0], sm.g.Bs[0], tid);
        return;
    }
    // ---- join block: batch b, hash column k ----
    int b = blk >> 7, k = blk & 127;
    const unsigned* kc = sigTk + (size_t)k * (NB * LK) + b * LK;
    const unsigned* qc = sigTq + (size_t)k * (NB * LQ) + b * LQ;
    uint4 kv = ((const uint4*)kc)[tid];   // j = tid*4 .. tid*4+3
    uint4 qv = ((const uint4*)qc)[tid];
    #pragma unroll
    for (int i = 0; i < 8; i++) sm.j.keys[i * 256 + tid] = 0xFFFFFFFFu;
    __syncthreads();
    // insert: 4 interleaved walks (independent CAS chains hide LDS latency)
    unsigned vvv[4] = {kv.x, kv.y, kv.z, kv.w};
    unsigned hh[4]; bool dn[4];
    #pragma unroll
    for (int e = 0; e < 4; e++) { hh[e] = (vvv[e] * 2654435761u) >> 21; dn[e] = false; }
    int rem = 4;
    while (rem) {
        #pragma unroll
        for (int e = 0; e < 4; e++) {
            if (dn[e]) continue;
            unsigned prev = atomicCAS(&sm.j.keys[hh[e]], 0xFFFFFFFFu, vvv[e]);
            if (prev == 0xFFFFFFFFu) {
                sm.j.vals[hh[e]] = (ushort_t)(tid * 4 + e);
                dn[e] = true; rem--;
            } else hh[e] = (hh[e] + 1) & 2047;
        }
    }
    __syncthreads();
    // probe: 4 interleaved walks; M atomicAdd result unused -> no stall
    uint8_t* Mb = M + ((size_t)b << 20);
    unsigned qq[4] = {qv.x, qv.y, qv.z, qv.w};
    #pragma unroll
    for (int e = 0; e < 4; e++) { hh[e] = (qq[e] * 2654435761u) >> 21; dn[e] = false; }
    rem = 4;
    while (rem) {
        unsigned kk[4];
        #pragma unroll
        for (int e = 0; e < 4; e++) kk[e] = sm.j.keys[hh[e]];  // 4 loads, 1 wait
        #pragma unroll
        for (int e = 0; e < 4; e++) {
            if (dn[e]) continue;
            if (kk[e] == 0xFFFFFFFFu) { dn[e] = true; rem--; }
            else {
                if (kk[e] == qq[e]) {
                    unsigned ix = ((unsigned)(tid * 4 + e) << 10) + sm.j.vals[hh[e]];
                    atomicAdd((unsigned*)(Mb + (ix & ~3u)), 1u << ((ix & 3u) * 8));
                }
                hh[e] = (hh[e] + 1) & 2047;
            }
        }
    }
}

// ---------------------------------------------------------------------------
// 3) g2: W2c = Vb @ Wvo^T (512 tiles, bf16)  ||  S[b,n] = vpsum[b,:].Wo[n,:]
// ---------------------------------------------------------------------------
__global__ __launch_bounds__(256) void g2_kernel(
        const ushort_t* __restrict__ Vb, const ushort_t* __restrict__ Wvo,
        ushort_t* __restrict__ W2c,
        const float* __restrict__ vpsum, const float* __restrict__ Wo,
        float* __restrict__ S) {
    __shared__ ushort_t As[2][64 * 32], Bs[2][64 * 32];
    int blk = blockIdx.x, tid = threadIdx.x;
    if (blk >= 512) {                     // ---- S role ----
        int sb = blk - 512, b = sb >> 1;
        int n = (sb & 1) * 256 + tid;
        const float* worow = Wo + (size_t)n * EDIM;
        const float* vps = vpsum + b * EDIM;
        float acc = 0.f;
        for (int e = 0; e < EDIM; e++) acc += vps[e] * worow[e];
        S[b * EDIM + n] = acc;
        return;
    }
    gemm64_dev<0, EPI_NONE>(Vb, Wvo, W2c,
                            EDIM, EDIM, EDIM, EDIM,
                            (blk >> 3) * 64, (blk & 7) * 64,
                            As[0], Bs[0], tid);
}

// ---------------------------------------------------------------------------
// 4) outk: one block per (b,q) row. Scans its own M row (1 KB, 4 chunks of
//    256 so LDS list capacity is exact), builds ΔP list, computes rs in-block
//    (deterministic), then out = (p0*S + Σ ΔP*W2c[j,:])/rs + bob.
//    No P matrix, no rs array, no global atomics.
// ---------------------------------------------------------------------------
__global__ __launch_bounds__(256) void outk_kernel(
        const uint8_t* __restrict__ M, const ushort_t* __restrict__ W2c,
        const float* __restrict__ S, const float* __restrict__ bob,
        float* __restrict__ out) {
    __shared__ unsigned lj[256];
    __shared__ float lp[256];
    __shared__ unsigned lcnt;
    int row = blockIdx.x, tid = threadIdx.x, b = row >> 10;
    const uint8_t* Mr = M + ((size_t)row << 10);
    float p0 = score_of(0);
    float acc0 = 0.f, acc1 = 0.f, drs = 0.f;
    int n0 = tid * 2;
    for (int c = 0; c < 4; c++) {
        if (tid == 0) lcnt = 0;
        __syncthreads();
        uint8_t m = Mr[c * 256 + tid];
        if (m) {
            unsigned s = atomicAdd(&lcnt, 1u);   // capacity 256 = exact bound
            lj[s] = c * 256 + tid;
            lp[s] = score_of((int)m) - p0;
        }
        __syncthreads();
        unsigned cnt = lcnt;
        for (unsigned i = 0; i < cnt; i++) {
            float w = lp[i];
            drs += w;                            // same order on all threads
            const ushort_t* wr = W2c + (((size_t)(b << 10) + lj[i]) << 9);
            unsigned pk = *(const unsigned*)(wr + n0);
            acc0 += w * __builtin_bit_cast(float, pk << 16);
            acc1 += w * __builtin_bit_cast(float, pk & 0xFFFF0000u);
        }
        __syncthreads();
    }
    float rs = 1024.0f * p0 + drs;
    float inv = 1.0f / rs;
    float2 sv = *(const float2*)(S + b * EDIM + n0);
    float2 bb = *(const float2*)(bob + n0);
    float2 o;
    o.x = (p0 * sv.x + acc0) * inv + bb.x;
    o.y = (p0 * sv.y + acc1) * inv + bb.y;
    *(float2*)(out + (size_t)row * EDIM + n0) = o;
}

// ---------------------------------------------------------------------------
extern "C" void kernel_launch(void* const* d_in, const int* in_sizes, int n_in,
                              void* d_out, int out_size, void* d_ws, size_t ws_size,
                              hipStream_t stream) {
    // inputs: 0 query 1 key 2 value 3 ts_q 4 ts_k 5 ha 6 hb 7 Wq 8 bq 9 Wk 10 bk
    //         11 Wv 12 bv 13 Wo 14 bo   (q/k projections are dead code)
    const float* value = (const float*)d_in[2];
    const int* tsq = (const int*)d_in[3];
    const int* tsk = (const int*)d_in[4];
    const int* ha  = (const int*)d_in[5];
    const int* hb  = (const int*)d_in[6];
    const float* Wv = (const float*)d_in[11];
    const float* bv = (const float*)d_in[12];
    const float* Wo = (const float*)d_in[13];
    const float* bo = (const float*)d_in[14];
    float* out = (float*)d_out;

    char* ws = (char*)d_ws;
    unsigned* sigTq = (unsigned*)(ws);                         // 2 MB [128][4096]
    unsigned* sigTk = (unsigned*)(ws + (2ull << 20));          // 2 MB [128][4096]
    uint8_t*  M     = (uint8_t*)(ws + (4ull << 20));           // 4 MB
    ushort_t* Vb    = (ushort_t*)(ws + (8ull << 20));          // 4 MB [4096 x 512]
    ushort_t* W2c   = (ushort_t*)(ws + (12ull << 20));         // 4 MB [4096 x 512]
    ushort_t* Wob   = (ushort_t*)(ws + (16ull << 20));         // 512 KB
    ushort_t* WvT   = (ushort_t*)(ws + (16ull << 20) + (512ull << 10)); // 512 KB
    ushort_t* Wvo   = (ushort_t*)(ws + (17ull << 20));         // 512 KB
    float* vbsum    = (float*)(ws + (17ull << 20) + (512ull << 10));    // 8 KB
    float* vpsum    = (float*)(ws + (17ull << 20) + (520ull << 10));    // 8 KB
    float* S        = (float*)(ws + (17ull << 20) + (528ull << 10));    // 8 KB
    float* bob      = (float*)(ws + (17ull << 20) + (536ull << 10));    // 2 KB

    // 1) converts + WvT + sigT + M zero + vbsum + bob
    prep_kernel<<<PREP_GRID, 256, 0, stream>>>(
        value, Wv, Wo, bv, bo, Vb, Wob, WvT,
        tsq, tsk, ha, hb, sigTq, sigTk, M, vbsum, bob);

    // 2) sparse join (512) || Wvo GEMM (64) || vpsum (8)
    joing1_kernel<<<584, 256, 0, stream>>>(
        sigTq, sigTk, M, Wob, WvT, Wvo, vbsum, Wv, vpsum);

    // 3) W2c = Vb @ Wvo^T (512) || S (8)
    g2_kernel<<<520, 256, 0, stream>>>(Vb, Wvo, W2c, vpsum, Wo, S);

    // 4) out[b,q,:] = (p0*S[b,:] + Σ ΔP*W2c[j,:]) / rs + bob
    outk_kernel<<<NB * LQ, 256, 0, stream>>>(M, W2c, S, bob, out);
}

// Round 9
// 161.167 us; speedup vs baseline: 1.3232x; 1.1017x over previous
//
#include <hip/hip_runtime.h>
#include <hip/hip_bf16.h>
#include <stdint.h>

// Problem constants (fixed by setup_inputs)
#define PRIME 2147483647u
#define GAMMA 0.3f
#define K_HASH 128
#define S_SET 8
#define NB 4
#define LQ 1024
#define LK 1024
#define EDIM 512

typedef unsigned short ushort_t;
typedef __attribute__((ext_vector_type(8))) short short8;
typedef __attribute__((ext_vector_type(4))) float f32x4;

static __device__ __forceinline__ unsigned short f2bf(float f) {
    unsigned u = __builtin_bit_cast(unsigned, f);
    u += 0x7FFFu + ((u >> 16) & 1u);   // RNE (no NaN in this problem)
    return (unsigned short)(u >> 16);
}

// async global->LDS, 16B per lane; LDS dst must be lane-contiguous.
static __device__ __forceinline__ void glds16(const void* g, void* l) {
    __builtin_amdgcn_global_load_lds(
        (const __attribute__((address_space(1))) unsigned int*)g,
        (__attribute__((address_space(3))) unsigned int*)l, 16, 0, 0);
}

#define SWZ(r) ((((r) >> 2) & 3) ^ ((r) & 3))

// score(m) = exp(exp(-GAMMA * 2S * (K-m)/(K+m))), m = matched hash slots
static __device__ __forceinline__ float score_of(int m) {
    float r = (float)(K_HASH - m) / (float)(K_HASH + m);
    return expf(expf(-GAMMA * (2.0f * S_SET) * r));
}

// ---------------------------------------------------------------------------
// 64x64-tile bf16 BT-GEMM device fn: C=A@B^T, f32 accum, 4 waves x 32x32,
// glds width-16, XOR-swizzled LDS, double-buffered.
// SEPI=1: additionally atomicAdd per-column f32 sums into Sacc[b][n]
// (b = m0>>10) -- the in-register column-sum epilogue (2 shuffles/wave).
// ---------------------------------------------------------------------------
template<int SEPI>
static __device__ void gemm64_dev(
        const ushort_t* __restrict__ A, const ushort_t* __restrict__ B,
        ushort_t* __restrict__ C, float* __restrict__ Sacc,
        int lda, int ldb, int ldc, int Kd, int m0, int n0,
        ushort_t* AsBase, ushort_t* BsBase, int tid) {
    ushort_t (*As)[64 * 32] = (ushort_t (*)[64 * 32])AsBase;
    ushort_t (*Bs)[64 * 32] = (ushort_t (*)[64 * 32])BsBase;
    int w = tid >> 6, lane = tid & 63;
    int wm = (w & 1) * 32, wn = (w >> 1) * 32;
    int mrow = lane & 15, kg = lane >> 4;

    int r = tid >> 2, c = (tid & 3) ^ SWZ(r);
    const ushort_t* pa = A + (size_t)(m0 + r) * lda + c * 8;
    const ushort_t* pb = B + (size_t)(n0 + r) * ldb + c * 8;

    int aoff[2], boff[2];
    #pragma unroll
    for (int s = 0; s < 2; s++) {
        int Ra = wm + s * 16 + mrow;
        aoff[s] = Ra * 32 + (kg ^ SWZ(Ra)) * 8;
        int Rb = wn + s * 16 + mrow;
        boff[s] = Rb * 32 + (kg ^ SWZ(Rb)) * 8;
    }

    f32x4 acc[2][2] = {};
    int nK = Kd >> 5;
    glds16(pa, &As[0][tid * 8]);
    glds16(pb, &Bs[0][tid * 8]);
    for (int i = 0; i < nK; i++) {
        __syncthreads();
        int cur = i & 1, nxt = cur ^ 1;
        if (i + 1 < nK) {
            int k0 = (i + 1) << 5;
            glds16(pa + k0, &As[nxt][tid * 8]);
            glds16(pb + k0, &Bs[nxt][tid * 8]);
        }
        short8 af[2], bh[2];
        #pragma unroll
        for (int s = 0; s < 2; s++) {
            af[s] = *(const short8*)&As[cur][aoff[s]];
            bh[s] = *(const short8*)&Bs[cur][boff[s]];
        }
        #pragma unroll
        for (int ii = 0; ii < 2; ii++)
            #pragma unroll
            for (int jj = 0; jj < 2; jj++)
                acc[ii][jj] = __builtin_amdgcn_mfma_f32_16x16x32_bf16(
                                  af[ii], bh[jj], acc[ii][jj], 0, 0, 0);
    }

    int col = lane & 15, rbase = (lane >> 4) * 4;
    #pragma unroll
    for (int ii = 0; ii < 2; ii++) {
        #pragma unroll
        for (int jj = 0; jj < 2; jj++) {
            #pragma unroll
            for (int rr = 0; rr < 4; rr++) {
                int gm = m0 + wm + ii * 16 + rbase + rr;
                int gn = n0 + wn + jj * 16 + col;
                C[(size_t)gm * ldc + gn] = f2bf(acc[ii][jj][rr]);
            }
        }
    }
    if (SEPI) {
        // column sums of this wave's 32 rows -> S[b][n], b = m0>>10
        #pragma unroll
        for (int jj = 0; jj < 2; jj++) {
            float s = 0.f;
            #pragma unroll
            for (int ii = 0; ii < 2; ii++)
                #pragma unroll
                for (int rr = 0; rr < 4; rr++) s += acc[ii][jj][rr];
            s += __shfl_xor(s, 16);          // reduce across the 4 row-groups
            s += __shfl_xor(s, 32);
            if ((lane >> 4) == 0)
                atomicAdd(&Sacc[(m0 >> 10) * EDIM + n0 + wn + jj * 16 + col], s);
        }
    }
}

// ---------------------------------------------------------------------------
// 1) prep (small roles FIRST so no straggler tail):
//    bob = bo + bv@Wo^T (wave-per-row coalesced reduce) | zero S |
//    value->Vb, Wo->Wob (bf16) | zero M | sigT[k][4096] (u32, LDS transpose) |
//    WvT = Wv^T (bf16 tiles).
// ---------------------------------------------------------------------------
#define BOB_BLOCKS 8
#define SZ_BLOCKS 1
#define CVT_N0 (NB * LK * EDIM)
#define CVT_N1 (EDIM * EDIM)
#define CVT_BLOCKS ((CVT_N0 + CVT_N1) / (256 * 8))   // 1152
#define MZ_BLOCKS 1024     // 4 MB M / 4 KB
#define SIGT_BLOCKS 128    // 8192 rows / 64 rows per block
#define WVT_BLOCKS 64      // 8x8 64x64 transpose tiles
#define PREP_GRID (BOB_BLOCKS + SZ_BLOCKS + CVT_BLOCKS + MZ_BLOCKS + SIGT_BLOCKS + WVT_BLOCKS)

__global__ __launch_bounds__(256) void prep_kernel(
        const float* __restrict__ value, const float* __restrict__ Wv,
        const float* __restrict__ Wo, const float* __restrict__ bv,
        const float* __restrict__ bo,
        ushort_t* __restrict__ Vb, ushort_t* __restrict__ Wob,
        ushort_t* __restrict__ WvT,
        const int* __restrict__ ts_q, const int* __restrict__ ts_k,
        const int* __restrict__ ha, const int* __restrict__ hb,
        unsigned* __restrict__ sigTq, unsigned* __restrict__ sigTk,
        uint8_t* __restrict__ M, float* __restrict__ S,
        float* __restrict__ bob) {
    __shared__ unsigned tile[128 * 65];   // sigT transpose / WvT (ushort view)
    __shared__ int ids_s[64 * S_SET];
    int blk = blockIdx.x, tid = threadIdx.x;
    if (blk < BOB_BLOCKS) {               // ---- bob: wave-per-row reduce ----
        int w = tid >> 6, lane = tid & 63;
        #pragma unroll
        for (int i = 0; i < 16; i++) {
            int row = blk * 64 + w * 16 + i;
            const float* wr = Wo + (size_t)row * EDIM;
            float s = 0.f;
            #pragma unroll
            for (int c2 = 0; c2 < 8; c2++)
                s += bv[lane + 64 * c2] * wr[lane + 64 * c2];
            #pragma unroll
            for (int off = 32; off; off >>= 1) s += __shfl_down(s, off);
            if (lane == 0) bob[row] = bo[row] + s;
        }
        return;
    }
    if (blk < BOB_BLOCKS + SZ_BLOCKS) {   // ---- zero S (8 KB) ----
        ((float2*)S)[tid] = (float2){0.f, 0.f};
        ((float2*)S)[256 + tid] = (float2){0.f, 0.f};
        ((float2*)S)[512 + tid] = (float2){0.f, 0.f};
        ((float2*)S)[768 + tid] = (float2){0.f, 0.f};
        return;
    }
    if (blk < BOB_BLOCKS + SZ_BLOCKS + CVT_BLOCKS) {  // ---- convert ----
        size_t i = ((size_t)(blk - BOB_BLOCKS - SZ_BLOCKS) * 256 + tid) * 8;
        const float* src; ushort_t* dst; size_t off;
        if (i < CVT_N0) { src = value; dst = Vb;  off = i; }
        else            { src = Wo;    dst = Wob; off = i - CVT_N0; }
        float4 a = *(const float4*)(src + off);
        float4 b = *(const float4*)(src + off + 4);
        ushort4 o0, o1;
        o0.x = f2bf(a.x); o0.y = f2bf(a.y); o0.z = f2bf(a.z); o0.w = f2bf(a.w);
        o1.x = f2bf(b.x); o1.y = f2bf(b.y); o1.z = f2bf(b.z); o1.w = f2bf(b.w);
        *(ushort4*)(dst + off)     = o0;
        *(ushort4*)(dst + off + 4) = o1;
        return;
    }
    if (blk < BOB_BLOCKS + SZ_BLOCKS + CVT_BLOCKS + MZ_BLOCKS) { // ---- zero M ----
        size_t off = ((size_t)(blk - BOB_BLOCKS - SZ_BLOCKS - CVT_BLOCKS) * 256 + tid) * 16;
        *(int4*)(M + off) = (int4){0, 0, 0, 0};
        return;
    }
    if (blk < BOB_BLOCKS + SZ_BLOCKS + CVT_BLOCKS + MZ_BLOCKS + SIGT_BLOCKS) {
        // ---- sigT: 64 rows x all 128 k, written column-major ----
        int sb = blk - (BOB_BLOCKS + SZ_BLOCKS + CVT_BLOCKS + MZ_BLOCKS);  // 0..127
        int r0 = sb * 64;                 // global row 0..8191 (q then k)
        const int* ts = (r0 < NB * LQ) ? ts_q : ts_k;
        unsigned* sigT = (r0 < NB * LQ) ? sigTq : sigTk;
        int base = r0 & (NB * LQ - 1);
        ((int2*)ids_s)[tid] = ((const int2*)(ts + (size_t)base * S_SET))[tid];
        __syncthreads();
        int kt = tid & 127, rt = tid >> 7;
        unsigned long long a  = (unsigned)ha[kt];
        unsigned long long bb = (unsigned)hb[kt];
        for (int r = rt; r < 64; r += 2) {
            unsigned mn = 0xFFFFFFFFu;
            #pragma unroll
            for (int s = 0; s < S_SET; s++) {
                unsigned long long x =
                    a * (unsigned long long)(unsigned)ids_s[r * S_SET + s] + bb;
                x = (x & PRIME) + (x >> 31);  // 2^31 == 1 (mod 2^31-1)
                x = (x & PRIME) + (x >> 31);
                unsigned rr = (unsigned)x;
                if (rr >= PRIME) rr -= PRIME;
                mn = (rr < mn) ? rr : mn;
            }
            tile[kt * 65 + r] = mn;
        }
        __syncthreads();
        #pragma unroll
        for (int ch = 0; ch < 32; ch++) {
            int idx = ch * 256 + tid;
            int k = idx >> 6, r = idx & 63;
            sigT[(size_t)k * (NB * LQ) + base + r] = tile[k * 65 + r];
        }
        return;
    }
    // ---- WvT: 64x64 transpose tiles, WvT[e][e'] = bf16(Wv[e'][e]) ----
    int wt = blk - (BOB_BLOCKS + SZ_BLOCKS + CVT_BLOCKS + MZ_BLOCKS + SIGT_BLOCKS);
    int r0 = (wt >> 3) * 64, c0 = (wt & 7) * 64;
    ushort_t (*tt)[65] = (ushort_t (*)[65])tile;
    #pragma unroll
    for (int p = 0; p < 16; p++) {
        int idx = p * 256 + tid, r = idx >> 6, c = idx & 63;
        tt[c][r] = f2bf(Wv[(size_t)(r0 + r) * EDIM + c0 + c]);
    }
    __syncthreads();
    #pragma unroll
    for (int p = 0; p < 16; p++) {
        int idx = p * 256 + tid, r = idx >> 6, c = idx & 63;
        WvT[(size_t)(c0 + r) * EDIM + r0 + c] = tt[r][c];
    }
}

// ---------------------------------------------------------------------------
// 2) joing1: Wvo = Wob@WvT^T (64 tiles, blk<64)  ||  sparse equality join
//    (512 blocks): one (b,k) per block, two contiguous 4 KB sigT columns,
//    2048-slot LDS table (dups kept -> exact multiplicity), 4-way interleaved
//    hash walks, fire-and-forget byte atomicAdds into M.
// ---------------------------------------------------------------------------
union JSmem {
    struct { unsigned keys[2048]; ushort_t vals[2048]; } j;   // 12 KB
    struct { ushort_t As[2][64 * 32]; ushort_t Bs[2][64 * 32]; } g; // 16 KB
};

__global__ __launch_bounds__(256) void joing1_kernel(
        const unsigned* __restrict__ sigTq, const unsigned* __restrict__ sigTk,
        uint8_t* __restrict__ M,
        const ushort_t* __restrict__ Wob, const ushort_t* __restrict__ WvT,
        ushort_t* __restrict__ Wvo) {
    __shared__ JSmem sm;
    int blk = blockIdx.x, tid = threadIdx.x;
    if (blk < 64) {                       // ---- Wvo[n,e] = Wob[n,:].WvT[e,:] ----
        gemm64_dev<0>(Wob, WvT, Wvo, nullptr,
                      EDIM, EDIM, EDIM, EDIM,
                      (blk >> 3) * 64, (blk & 7) * 64,
                      sm.g.As[0], sm.g.Bs[0], tid);
        return;
    }
    // ---- join block: batch b, hash column k ----
    int jt = blk - 64, b = jt >> 7, k = jt & 127;
    const unsigned* kc = sigTk + (size_t)k * (NB * LK) + b * LK;
    const unsigned* qc = sigTq + (size_t)k * (NB * LQ) + b * LQ;
    uint4 kv = ((const uint4*)kc)[tid];   // j = tid*4 .. tid*4+3
    uint4 qv = ((const uint4*)qc)[tid];
    #pragma unroll
    for (int i = 0; i < 8; i++) sm.j.keys[i * 256 + tid] = 0xFFFFFFFFu;
    __syncthreads();
    // insert: 4 interleaved walks (independent CAS chains hide LDS latency)
    unsigned vvv[4] = {kv.x, kv.y, kv.z, kv.w};
    unsigned hh[4]; bool dn[4];
    #pragma unroll
    for (int e = 0; e < 4; e++) { hh[e] = (vvv[e] * 2654435761u) >> 21; dn[e] = false; }
    int rem = 4;
    while (rem) {
        #pragma unroll
        for (int e = 0; e < 4; e++) {
            if (dn[e]) continue;
            unsigned prev = atomicCAS(&sm.j.keys[hh[e]], 0xFFFFFFFFu, vvv[e]);
            if (prev == 0xFFFFFFFFu) {
                sm.j.vals[hh[e]] = (ushort_t)(tid * 4 + e);
                dn[e] = true; rem--;
            } else hh[e] = (hh[e] + 1) & 2047;
        }
    }
    __syncthreads();
    // probe: 4 interleaved walks; M atomicAdd result unused -> no stall
    uint8_t* Mb = M + ((size_t)b << 20);
    unsigned qq[4] = {qv.x, qv.y, qv.z, qv.w};
    #pragma unroll
    for (int e = 0; e < 4; e++) { hh[e] = (qq[e] * 2654435761u) >> 21; dn[e] = false; }
    rem = 4;
    while (rem) {
        unsigned kk[4];
        #pragma unroll
        for (int e = 0; e < 4; e++) kk[e] = sm.j.keys[hh[e]];  // 4 loads, 1 wait
        #pragma unroll
        for (int e = 0; e < 4; e++) {
            if (dn[e]) continue;
            if (kk[e] == 0xFFFFFFFFu) { dn[e] = true; rem--; }
            else {
                if (kk[e] == qq[e]) {
                    unsigned ix = ((unsigned)(tid * 4 + e) << 10) + sm.j.vals[hh[e]];
                    atomicAdd((unsigned*)(Mb + (ix & ~3u)), 1u << ((ix & 3u) * 8));
                }
                hh[e] = (hh[e] + 1) & 2047;
            }
        }
    }
}

// ---------------------------------------------------------------------------
// 3) g2: W2c = Vb @ Wvo^T (512 tiles) with in-epilogue column-sum S (no
//    separate S role -> no straggler tail).
// ---------------------------------------------------------------------------
__global__ __launch_bounds__(256) void g2_kernel(
        const ushort_t* __restrict__ Vb, const ushort_t* __restrict__ Wvo,
        ushort_t* __restrict__ W2c, float* __restrict__ S) {
    __shared__ ushort_t As[2][64 * 32], Bs[2][64 * 32];
    int blk = blockIdx.x;
    gemm64_dev<1>(Vb, Wvo, W2c, S,
                  EDIM, EDIM, EDIM, EDIM,
                  (blk >> 3) * 64, (blk & 7) * 64,
                  As[0], Bs[0], threadIdx.x);
}

// ---------------------------------------------------------------------------
// 4) outk: one block per (b,q) row. Scans its own M row (1 KB, 4 chunks of
//    256 so LDS list capacity is exact), builds ΔP list, computes rs in-block
//    (deterministic), then out = (p0*S + Σ ΔP*W2c[j,:])/rs + bob.
//    No P matrix, no rs array, no global atomics.
// ---------------------------------------------------------------------------
__global__ __launch_bounds__(256) void outk_kernel(
        const uint8_t* __restrict__ M, const ushort_t* __restrict__ W2c,
        const float* __restrict__ S, const float* __restrict__ bob,
        float* __restrict__ out) {
    __shared__ unsigned lj[256];
    __shared__ float lp[256];
    __shared__ unsigned lcnt;
    int row = blockIdx.x, tid = threadIdx.x, b = row >> 10;
    const uint8_t* Mr = M + ((size_t)row << 10);
    float p0 = score_of(0);
    float acc0 = 0.f, acc1 = 0.f, drs = 0.f;
    int n0 = tid * 2;
    for (int c = 0; c < 4; c++) {
        if (tid == 0) lcnt = 0;
        __syncthreads();
        uint8_t m = Mr[c * 256 + tid];
        if (m) {
            unsigned s = atomicAdd(&lcnt, 1u);   // capacity 256 = exact bound
            lj[s] = c * 256 + tid;
            lp[s] = score_of((int)m) - p0;
        }
        __syncthreads();
        unsigned cnt = lcnt;
        for (unsigned i = 0; i < cnt; i++) {
            float w = lp[i];
            drs += w;                            // same order on all threads
            const ushort_t* wr = W2c + (((size_t)(b << 10) + lj[i]) << 9);
            unsigned pk = *(const unsigned*)(wr + n0);
            acc0 += w * __builtin_bit_cast(float, pk << 16);
            acc1 += w * __builtin_bit_cast(float, pk & 0xFFFF0000u);
        }
        __syncthreads();
    }
    float rs = 1024.0f * p0 + drs;
    float inv = 1.0f / rs;
    float2 sv = *(const float2*)(S + b * EDIM + n0);
    float2 bb = *(const float2*)(bob + n0);
    float2 o;
    o.x = (p0 * sv.x + acc0) * inv + bb.x;
    o.y = (p0 * sv.y + acc1) * inv + bb.y;
    *(float2*)(out + (size_t)row * EDIM + n0) = o;
}

// ---------------------------------------------------------------------------
extern "C" void kernel_launch(void* const* d_in, const int* in_sizes, int n_in,
                              void* d_out, int out_size, void* d_ws, size_t ws_size,
                              hipStream_t stream) {
    // inputs: 0 query 1 key 2 value 3 ts_q 4 ts_k 5 ha 6 hb 7 Wq 8 bq 9 Wk 10 bk
    //         11 Wv 12 bv 13 Wo 14 bo   (q/k projections are dead code)
    const float* value = (const float*)d_in[2];
    const int* tsq = (const int*)d_in[3];
    const int* tsk = (const int*)d_in[4];
    const int* ha  = (const int*)d_in[5];
    const int* hb  = (const int*)d_in[6];
    const float* Wv = (const float*)d_in[11];
    const float* bv = (const float*)d_in[12];
    const float* Wo = (const float*)d_in[13];
    const float* bo = (const float*)d_in[14];
    float* out = (float*)d_out;

    char* ws = (char*)d_ws;
    unsigned* sigTq = (unsigned*)(ws);                         // 2 MB [128][4096]
    unsigned* sigTk = (unsigned*)(ws + (2ull << 20));          // 2 MB [128][4096]
    uint8_t*  M     = (uint8_t*)(ws + (4ull << 20));           // 4 MB
    ushort_t* Vb    = (ushort_t*)(ws + (8ull << 20));          // 4 MB [4096 x 512]
    ushort_t* W2c   = (ushort_t*)(ws + (12ull << 20));         // 4 MB [4096 x 512]
    ushort_t* Wob   = (ushort_t*)(ws + (16ull << 20));         // 512 KB
    ushort_t* WvT   = (ushort_t*)(ws + (16ull << 20) + (512ull << 10)); // 512 KB
    ushort_t* Wvo   = (ushort_t*)(ws + (17ull << 20));         // 512 KB
    float* S        = (float*)(ws + (17ull << 20) + (512ull << 10));    // 8 KB
    float* bob      = (float*)(ws + (17ull << 20) + (520ull << 10));    // 2 KB

    // 1) bob + S zero + converts + M zero + sigT + WvT (small roles first)
    prep_kernel<<<PREP_GRID, 256, 0, stream>>>(
        value, Wv, Wo, bv, bo, Vb, Wob, WvT,
        tsq, tsk, ha, hb, sigTq, sigTk, M, S, bob);

    // 2) Wvo GEMM (64) || sparse join (512)
    joing1_kernel<<<576, 256, 0, stream>>>(
        sigTq, sigTk, M, Wob, WvT, Wvo);

    // 3) W2c = Vb @ Wvo^T (512 tiles) with column-sum S epilogue
    g2_kernel<<<512, 256, 0, stream>>>(Vb, Wvo, W2c, S);

    // 4) out[b,q,:] = (p0*S[b,:] + Σ ΔP*W2c[j,:]) / rs + bob
    outk_kernel<<<NB * LQ, 256, 0, stream>>>(M, W2c, S, bob, out);
}